// Round 14
// baseline (83.969 us; speedup 1.0000x reference)
//
#include <hip/hip_runtime.h>
#include <cstddef>

// B=2048, N=64, C_IN=512, C_H=128, NUM_CLASSES=2, E=1024
#define NN   64
#define CIN  512
#define CH   128

typedef unsigned short ushort_t;
typedef __attribute__((ext_vector_type(8))) short bf16x8;
typedef __attribute__((ext_vector_type(4))) short bf16x4;
typedef __attribute__((ext_vector_type(4))) float f32x4;

__device__ __forceinline__ ushort_t f2bf(float f) {          // RN-even fp32->bf16
    union { float f; unsigned u; } v; v.f = f;
    unsigned r = v.u + 0x7fffu + ((v.u >> 16) & 1u);
    return (ushort_t)(r >> 16);
}
__device__ __forceinline__ float bf2f(ushort_t b) {
    union { unsigned u; float f; } v; v.u = ((unsigned)b) << 16;
    return v.f;
}

// ---------------------------------------------------------------------------
// Kernel 1: block 0 builds normalized adjacency A (hi/lo bf16); blocks 1..64
// transpose + bf16 W1 (hi only) and W2 (hi only).
// ---------------------------------------------------------------------------
__global__ __launch_bounds__(256) void prep_all(const int* __restrict__ ei, int E,
                                                const float* __restrict__ W1,
                                                const float* __restrict__ W2,
                                                ushort_t* __restrict__ Ah, ushort_t* __restrict__ Al,
                                                ushort_t* __restrict__ W1h,
                                                ushort_t* __restrict__ W2h) {
    const int t = threadIdx.x;
    if (blockIdx.x == 0) {
        __shared__ float sdeg[NN];
        __shared__ float snorm[NN];
        __shared__ float sA[NN * NN];
        if (t < NN) sdeg[t] = 0.f;
        for (int i = t; i < NN * NN; i += 256) sA[i] = 0.f;
        __syncthreads();
        for (int e = t; e < E; e += 256) atomicAdd(&sdeg[ei[E + e]], 1.0f);
        __syncthreads();
        if (t < NN) snorm[t] = rsqrtf(sdeg[t] + 1.0f);
        __syncthreads();
        for (int e = t; e < E; e += 256) {
            int s = ei[e], d = ei[E + e];
            atomicAdd(&sA[d * NN + s], snorm[s] * snorm[d]);
        }
        if (t < NN) atomicAdd(&sA[t * NN + t], snorm[t] * snorm[t]);
        __syncthreads();
        for (int i = t; i < NN * NN; i += 256) {
            float a = sA[i];
            ushort_t h = f2bf(a);
            Ah[i] = h;
            Al[i] = f2bf(a - bf2f(h));
        }
    } else {
        const int idx = (blockIdx.x - 1) * 256 + t;
        const int stride = 64 * 256;
        for (int i = idx; i < CIN * CH; i += stride) {
            int k = i / CH, c = i % CH;
            W1h[c * CIN + k] = f2bf(W1[i]);          // hi only
        }
        for (int i = idx; i < CH * CH; i += stride) {
            int k = i / CH, c = i % CH;
            W2h[c * CH + k] = f2bf(W2[i]);           // hi only
        }
    }
}

// ---------------------------------------------------------------------------
// Kernel 2: FULLY FUSED — R14: BARRIER-FREE gemm1.
// W1h (128KB) is staged into LDS ONCE; the K-loop has no __syncthreads(),
// no ds_writes: each wave free-runs {convert X, issue next X, 16 ds_read,
// 32 MFMA} per chunk — waves drift and mutually hide X HBM latency (the
// R9..R13 per-chunk barrier drained the X prefetch queue every chunk).
// Block = 4 batches (256 rows), 512 thr = 8 waves x 32 rows (rf=2, ct=8) —
// per-wave register/LDS-read density identical to R13. 1 block/CU (128KB).
// Tail aliases the W1 region after one barrier:
//   sYt 4 x [128c][64n] at elems [0,32768); sH1 4 x [64n][128c] at
//   [32768,65536); sW2 [128c][128k] at [0,16384) (overlays dead Y1 of
//   batches 0,1 — staged after agg1, consumed before Y2 writeback).
// 16B-granule XOR swizzle everywhere: granule g of row r at slot g^(r&7)
// (low-3-bit XOR, bijective within each 8-granule group; both-sides).
// ---------------------------------------------------------------------------
__global__ __launch_bounds__(512, 2) void fused_all(
    const float* __restrict__ x,
    const ushort_t* __restrict__ W1h,
    const ushort_t* __restrict__ Ah, const ushort_t* __restrict__ Al,
    const ushort_t* __restrict__ W2h,
    const float* __restrict__ b1, const float* __restrict__ b2,
    const float* __restrict__ fcW, const float* __restrict__ fcb,
    float* __restrict__ out)
{
    __shared__ ushort_t lds[65536];     // 131072 B
    __shared__ float sred[16];

    const int t   = threadIdx.x;
    const int l   = t & 63;
    const int w   = t >> 6;             // 0..7
    const int lr  = l & 15;
    const int lk  = l >> 4;
    const int lr7 = lr & 7;
    const size_t rbase = (size_t)blockIdx.x * 256;

    const float* xp0 = x + (rbase + w * 32 + lr) * CIN + lk * 8;
    float4 xraw[2][2][2];               // [rf][ks][half] next-chunk X

    // ---- prologue: issue X chunk 0 first (HBM fires under W staging) ----
    #pragma unroll
    for (int rf = 0; rf < 2; ++rf) {
        const float* xp = xp0 + rf * 16 * CIN;
        xraw[rf][0][0] = *reinterpret_cast<const float4*>(xp);
        xraw[rf][0][1] = *reinterpret_cast<const float4*>(xp + 4);
        xraw[rf][1][0] = *reinterpret_cast<const float4*>(xp + 32);
        xraw[rf][1][1] = *reinterpret_cast<const float4*>(xp + 36);
    }
    // ---- stage ALL of W1h into LDS (swizzled): 8192 granules / 512 thr ----
    #pragma unroll
    for (int u = 0; u < 16; ++u) {
        int idx = u * 512 + t;          // granule id
        int c = idx >> 6, g = idx & 63; // row c (0..127), granule g (0..63)
        *reinterpret_cast<bf16x8*>(&lds[c * 512 + ((g ^ (c & 7)) << 3)]) =
            *reinterpret_cast<const bf16x8*>(W1h + (size_t)c * CIN + g * 8);
    }
    __syncthreads();

    f32x4 acc[2][8];
    #pragma unroll
    for (int rf = 0; rf < 2; ++rf)
        #pragma unroll
        for (int ct = 0; ct < 8; ++ct)
            #pragma unroll
            for (int i = 0; i < 4; ++i) acc[rf][ct][i] = 0.f;

    // ---- gemm1: Y1 = (Xh + Xl) @ W1h — ZERO barriers ----
    for (int kc = 0; kc < 8; ++kc) {
        // convert previously-loaded X -> bf16 hi/lo
        bf16x8 xh[2][2], xl[2][2];
        #pragma unroll
        for (int rf = 0; rf < 2; ++rf)
            #pragma unroll
            for (int ks = 0; ks < 2; ++ks) {
                const float xv[8] = {xraw[rf][ks][0].x, xraw[rf][ks][0].y,
                                     xraw[rf][ks][0].z, xraw[rf][ks][0].w,
                                     xraw[rf][ks][1].x, xraw[rf][ks][1].y,
                                     xraw[rf][ks][1].z, xraw[rf][ks][1].w};
                #pragma unroll
                for (int j = 0; j < 8; ++j) {
                    ushort_t hh = f2bf(xv[j]);
                    xh[rf][ks][j] = (short)hh;
                    xl[rf][ks][j] = (short)f2bf(xv[j] - bf2f(hh));
                }
            }
        // issue next-chunk X loads (covered by this chunk's compute)
        if (kc < 7) {
            #pragma unroll
            for (int rf = 0; rf < 2; ++rf) {
                const float* xp = xp0 + rf * 16 * CIN + (kc + 1) * 64;
                xraw[rf][0][0] = *reinterpret_cast<const float4*>(xp);
                xraw[rf][0][1] = *reinterpret_cast<const float4*>(xp + 4);
                xraw[rf][1][0] = *reinterpret_cast<const float4*>(xp + 32);
                xraw[rf][1][1] = *reinterpret_cast<const float4*>(xp + 36);
            }
        }
        // compute chunk kc: W fragments from resident LDS
        #pragma unroll
        for (int ks = 0; ks < 2; ++ks) {
            #pragma unroll
            for (int ct = 0; ct < 8; ++ct) {
                const int c = ct * 16 + lr;
                const int gk = kc * 8 + (((ks << 2) | lk) ^ (c & 7));
                bf16x8 wh = *reinterpret_cast<const bf16x8*>(&lds[c * 512 + gk * 8]);
                #pragma unroll
                for (int rf = 0; rf < 2; ++rf) {
                    acc[rf][ct] = __builtin_amdgcn_mfma_f32_16x16x32_bf16(xh[rf][ks], wh, acc[rf][ct], 0, 0, 0);
                    acc[rf][ct] = __builtin_amdgcn_mfma_f32_16x16x32_bf16(xl[rf][ks], wh, acc[rf][ct], 0, 0, 0);
                }
            }
        }
    }
    __syncthreads();                    // gemm1 done; W1h region now dead

    // ================= tail (in-block, 4 batches) =================
    // sYt: batch qb at lds[qb*8192], tile [c(128)][n(64)] swizzled.
    // sH1: batch qb at lds[32768 + qb*8192], tile [n(64)][c(128)] swizzled.

    // ---- Y1 (registers) -> sYt, bf16 ----
    #pragma unroll
    for (int rf = 0; rf < 2; ++rf) {
        const int grow = w * 32 + rf * 16 + lk * 4;   // 0..255
        const int qb   = grow >> 6;
        const int n0   = grow & 63;
        const int gn   = n0 >> 3, noff = n0 & 7;
        #pragma unroll
        for (int ct = 0; ct < 8; ++ct) {
            const int c = ct * 16 + lr;
            bf16x4 yv;
            #pragma unroll
            for (int r = 0; r < 4; ++r) yv[r] = (short)f2bf(acc[rf][ct][r]);
            *reinterpret_cast<bf16x4*>(&lds[qb * 8192 + c * 64 + ((gn ^ lr7) << 3) + noff]) = yv;
        }
    }
    __syncthreads();

    const int q = w >> 1;               // batch within block (0..3)
    const int h = w & 1;                // 32-row half
    ushort_t* sYtq = &lds[q * 8192];
    ushort_t* sH1q = &lds[32768 + q * 8192];

    // ---- agg1: H1 = relu(A @ Y1 + b1) -> sH1 ----
    bf16x8 ahf[2][2], alf[2][2];        // [rf][ks]
    #pragma unroll
    for (int rf = 0; rf < 2; ++rf)
        #pragma unroll
        for (int ks = 0; ks < 2; ++ks) {
            const int nrow = h * 32 + rf * 16 + lr;
            const int ko = ks * 32 + lk * 8;
            ahf[rf][ks] = *reinterpret_cast<const bf16x8*>(Ah + nrow * NN + ko);
            alf[rf][ks] = *reinterpret_cast<const bf16x8*>(Al + nrow * NN + ko);
        }
    {
        f32x4 hacc[2][8];
        #pragma unroll
        for (int rf = 0; rf < 2; ++rf)
            #pragma unroll
            for (int ct = 0; ct < 8; ++ct)
                #pragma unroll
                for (int i = 0; i < 4; ++i) hacc[rf][ct][i] = 0.f;
        #pragma unroll
        for (int ks = 0; ks < 2; ++ks) {
            const int swz = (((ks << 2) | lk) ^ lr7) << 3;
            #pragma unroll
            for (int ct = 0; ct < 8; ++ct) {
                const int c = ct * 16 + lr;
                bf16x8 y = *reinterpret_cast<const bf16x8*>(&sYtq[c * 64 + swz]);
                #pragma unroll
                for (int rf = 0; rf < 2; ++rf) {
                    hacc[rf][ct] = __builtin_amdgcn_mfma_f32_16x16x32_bf16(ahf[rf][ks], y, hacc[rf][ct], 0, 0, 0);
                    hacc[rf][ct] = __builtin_amdgcn_mfma_f32_16x16x32_bf16(alf[rf][ks], y, hacc[rf][ct], 0, 0, 0);
                }
            }
        }
        #pragma unroll
        for (int rf = 0; rf < 2; ++rf)
            #pragma unroll
            for (int ct = 0; ct < 8; ++ct) {
                const int c = ct * 16 + lr;
                const int gc = c >> 3;
                const float bias = b1[c];
                #pragma unroll
                for (int r = 0; r < 4; ++r) {
                    const int n = h * 32 + rf * 16 + lk * 4 + r;
                    float v = fmaxf(hacc[rf][ct][r] + bias, 0.f);
                    sH1q[n * 128 + ((gc ^ (n & 7)) << 3) + (c & 7)] = f2bf(v);
                }
            }
    }
    __syncthreads();

    // ---- stage W2h into LDS at [0,16384) (dead Y1 of batches 0,1) ----
    #pragma unroll
    for (int u = 0; u < 4; ++u) {
        int idx = u * 512 + t;          // granule id 0..2047
        int c = idx >> 4, g = idx & 15;
        *reinterpret_cast<bf16x8*>(&lds[c * 128 + ((g ^ (c & 7)) << 3)]) =
            *reinterpret_cast<const bf16x8*>(W2h + (size_t)c * CH + g * 8);
    }
    __syncthreads();

    // ---- gemm2: Y2 = H1 @ W2h (1-pass), W2 from LDS ----
    f32x4 acc2[2][8];
    #pragma unroll
    for (int rf = 0; rf < 2; ++rf)
        #pragma unroll
        for (int ct = 0; ct < 8; ++ct)
            #pragma unroll
            for (int i = 0; i < 4; ++i) acc2[rf][ct][i] = 0.f;
    {
        bf16x8 hf[2][4];                // [rf][ks], K=128
        #pragma unroll
        for (int rf = 0; rf < 2; ++rf) {
            const int n = h * 32 + rf * 16 + lr;
            #pragma unroll
            for (int ks = 0; ks < 4; ++ks) {
                const int gh = ((ks << 2) | lk) ^ (n & 7);
                hf[rf][ks] = *reinterpret_cast<const bf16x8*>(&sH1q[n * 128 + (gh << 3)]);
            }
        }
        #pragma unroll
        for (int ct = 0; ct < 8; ++ct) {
            const int c = ct * 16 + lr;
            #pragma unroll
            for (int ks = 0; ks < 4; ++ks) {
                const int gw = ((ks << 2) | lk) ^ (c & 7);
                bf16x8 w2 = *reinterpret_cast<const bf16x8*>(&lds[c * 128 + (gw << 3)]);
                #pragma unroll
                for (int rf = 0; rf < 2; ++rf)
                    acc2[rf][ct] = __builtin_amdgcn_mfma_f32_16x16x32_bf16(hf[rf][ks], w2, acc2[rf][ct], 0, 0, 0);
            }
        }
    }
    __syncthreads();                    // all W2h reads done before Y2 overwrite

    // Y2 -> sYt
    #pragma unroll
    for (int rf = 0; rf < 2; ++rf) {
        const int n0 = h * 32 + rf * 16 + lk * 4;
        const int gn = n0 >> 3, noff = n0 & 7;
        #pragma unroll
        for (int ct = 0; ct < 8; ++ct) {
            const int c = ct * 16 + lr;
            bf16x4 yv;
            #pragma unroll
            for (int r = 0; r < 4; ++r) yv[r] = (short)f2bf(acc2[rf][ct][r]);
            *reinterpret_cast<bf16x4*>(&sYtq[c * 64 + ((gn ^ lr7) << 3) + noff]) = yv;
        }
    }
    __syncthreads();

    // ---- agg2 + bias + relu + FC ----
    float p0 = 0.f, p1 = 0.f;
    {
        f32x4 h2[2][8];
        #pragma unroll
        for (int rf = 0; rf < 2; ++rf)
            #pragma unroll
            for (int ct = 0; ct < 8; ++ct)
                #pragma unroll
                for (int i = 0; i < 4; ++i) h2[rf][ct][i] = 0.f;
        #pragma unroll
        for (int ks = 0; ks < 2; ++ks) {
            const int swz = (((ks << 2) | lk) ^ lr7) << 3;
            #pragma unroll
            for (int ct = 0; ct < 8; ++ct) {
                const int c = ct * 16 + lr;
                bf16x8 y = *reinterpret_cast<const bf16x8*>(&sYtq[c * 64 + swz]);
                #pragma unroll
                for (int rf = 0; rf < 2; ++rf) {
                    h2[rf][ct] = __builtin_amdgcn_mfma_f32_16x16x32_bf16(ahf[rf][ks], y, h2[rf][ct], 0, 0, 0);
                    h2[rf][ct] = __builtin_amdgcn_mfma_f32_16x16x32_bf16(alf[rf][ks], y, h2[rf][ct], 0, 0, 0);
                }
            }
        }
        #pragma unroll
        for (int rf = 0; rf < 2; ++rf)
            #pragma unroll
            for (int ct = 0; ct < 8; ++ct) {
                const int c = ct * 16 + lr;
                const float bias = b2[c];
                #pragma unroll
                for (int r = 0; r < 4; ++r) {
                    const int n = h * 32 + rf * 16 + lk * 4 + r;
                    float v = fmaxf(h2[rf][ct][r] + bias, 0.f);
                    const float2 fw = *reinterpret_cast<const float2*>(fcW + ((size_t)(n * CH + c)) * 2);
                    p0 = fmaf(v, fw.x, p0);
                    p1 = fmaf(v, fw.y, p1);
                }
            }
    }
    #pragma unroll
    for (int off = 32; off > 0; off >>= 1) {
        p0 += __shfl_down(p0, off);
        p1 += __shfl_down(p1, off);
    }
    if (l == 0) { sred[w * 2] = p0; sred[w * 2 + 1] = p1; }
    __syncthreads();
    if (t == 0) {
        const size_t bA = (size_t)blockIdx.x * 4;
        #pragma unroll
        for (int qb = 0; qb < 4; ++qb) {
            out[(bA + qb) * 2 + 0] = sred[4 * qb + 0] + sred[4 * qb + 2] + fcb[0];
            out[(bA + qb) * 2 + 1] = sred[4 * qb + 1] + sred[4 * qb + 3] + fcb[1];
        }
    }
}

// ---------------------------------------------------------------------------
extern "C" void kernel_launch(void* const* d_in, const int* in_sizes, int n_in,
                              void* d_out, int out_size, void* d_ws, size_t ws_size,
                              hipStream_t stream) {
    const float* x   = (const float*)d_in[0];
    const int*   ei  = (const int*)d_in[1];
    const float* W1  = (const float*)d_in[2];
    const float* b1  = (const float*)d_in[3];
    const float* W2  = (const float*)d_in[4];
    const float* b2  = (const float*)d_in[5];
    const float* fcW = (const float*)d_in[6];
    const float* fcb = (const float*)d_in[7];
    float* outp = (float*)d_out;

    // ws layout (bf16 elems): Ah,Al [64*64]; W1h [128*512]; W2h [128*128]
    ushort_t* Ah  = (ushort_t*)d_ws;
    ushort_t* Al  = Ah + NN * NN;
    ushort_t* W1h = Al + NN * NN;
    ushort_t* W2h = W1h + CIN * CH;    // total 180224 B

    const int E  = in_sizes[1] / 2;
    const int Bn = in_sizes[0] / (NN * CIN);

    prep_all<<<65, 256, 0, stream>>>(ei, E, W1, W2, Ah, Al, W1h, W2h);
    fused_all<<<Bn / 4, 512, 0, stream>>>(x, W1h, Ah, Al, W2h,
                                          b1, b2, fcW, fcb, outp);
}

// Round 15
// 77.712 us; speedup vs baseline: 1.0805x; 1.0805x over previous
//
#include <hip/hip_runtime.h>
#include <cstddef>

// B=2048, N=64, C_IN=512, C_H=128, NUM_CLASSES=2, E=1024
#define NN   64
#define CIN  512
#define CH   128

typedef unsigned short ushort_t;
typedef __attribute__((ext_vector_type(8))) short bf16x8;
typedef __attribute__((ext_vector_type(4))) short bf16x4;
typedef __attribute__((ext_vector_type(4))) float f32x4;

__device__ __forceinline__ ushort_t f2bf(float f) {          // RN-even fp32->bf16
    union { float f; unsigned u; } v; v.f = f;
    unsigned r = v.u + 0x7fffu + ((v.u >> 16) & 1u);
    return (ushort_t)(r >> 16);
}
__device__ __forceinline__ float bf2f(ushort_t b) {
    union { unsigned u; float f; } v; v.u = ((unsigned)b) << 16;
    return v.f;
}

// ---------------------------------------------------------------------------
// Kernel 1: block 0 builds normalized adjacency A (hi/lo bf16); blocks 1..64
// transpose + bf16 W1 (hi only) and W2 (hi only).
// ---------------------------------------------------------------------------
__global__ __launch_bounds__(256) void prep_all(const int* __restrict__ ei, int E,
                                                const float* __restrict__ W1,
                                                const float* __restrict__ W2,
                                                ushort_t* __restrict__ Ah, ushort_t* __restrict__ Al,
                                                ushort_t* __restrict__ W1h,
                                                ushort_t* __restrict__ W2h) {
    const int t = threadIdx.x;
    if (blockIdx.x == 0) {
        __shared__ float sdeg[NN];
        __shared__ float snorm[NN];
        __shared__ float sA[NN * NN];
        if (t < NN) sdeg[t] = 0.f;
        for (int i = t; i < NN * NN; i += 256) sA[i] = 0.f;
        __syncthreads();
        for (int e = t; e < E; e += 256) atomicAdd(&sdeg[ei[E + e]], 1.0f);
        __syncthreads();
        if (t < NN) snorm[t] = rsqrtf(sdeg[t] + 1.0f);
        __syncthreads();
        for (int e = t; e < E; e += 256) {
            int s = ei[e], d = ei[E + e];
            atomicAdd(&sA[d * NN + s], snorm[s] * snorm[d]);
        }
        if (t < NN) atomicAdd(&sA[t * NN + t], snorm[t] * snorm[t]);
        __syncthreads();
        for (int i = t; i < NN * NN; i += 256) {
            float a = sA[i];
            ushort_t h = f2bf(a);
            Ah[i] = h;
            Al[i] = f2bf(a - bf2f(h));
        }
    } else {
        const int idx = (blockIdx.x - 1) * 256 + t;
        const int stride = 64 * 256;
        for (int i = idx; i < CIN * CH; i += stride) {
            int k = i / CH, c = i % CH;
            W1h[c * CIN + k] = f2bf(W1[i]);          // hi only
        }
        for (int i = idx; i < CH * CH; i += stride) {
            int k = i / CH, c = i % CH;
            W2h[c * CH + k] = f2bf(W2[i]);           // hi only
        }
    }
}

// ---------------------------------------------------------------------------
// Kernel 2: FULLY FUSED — R15 = R11-reshape with the diagnosed fixes.
// ONE BATCH per block (64 rows), 256 thr = 4 waves x 16 rows (ct=8).
// __launch_bounds__(256,3): VGPR cap ~170 >> natural demand ~130, so the
// compiler has no pressure to sink the X/W prefetches (R6/R7/R11 failure).
// LDS 32KB -> 3 blocks/CU (VGPR-capped) = 3 INDEPENDENT barrier domains
// per CU (vs R13's 2): while one block drains vmcnt at its chunk barrier,
// two others keep X flowing.
// Inner loops identical to R13: W1 LDS dbuf (reg-staged, swizzled), 1-deep
// X register prefetch, 2-pass split-bf16 gemm1, 1-pass gemm2/W2h.
// LDS map (elems): gemm1 W dbuf [0,8192)+[8192,16384).
//   tail: sYt [128c][64n] = [0,8192); sH1 [64n][128c] = [8192,16384);
//         W2h staged in TWO k-halves [128c][64k] into [0,8192) (dead sYt),
//         consumed before Y2 writeback. 16B-granule XOR swizzle everywhere:
//         granule g of row r at slot g^(r&7) (both-sides, bijective).
// ---------------------------------------------------------------------------
__global__ __launch_bounds__(256, 3) void fused_all(
    const float* __restrict__ x,
    const ushort_t* __restrict__ W1h,
    const ushort_t* __restrict__ Ah, const ushort_t* __restrict__ Al,
    const ushort_t* __restrict__ W2h,
    const float* __restrict__ b1, const float* __restrict__ b2,
    const float* __restrict__ fcW, const float* __restrict__ fcb,
    float* __restrict__ out)
{
    __shared__ ushort_t lds[16384];     // 32768 B
    __shared__ float sred[8];

    const int t   = threadIdx.x;
    const int l   = t & 63;
    const int w   = t >> 6;             // 0..3
    const int lr  = l & 15;
    const int lk  = l >> 4;
    const int lr7 = lr & 7;
    const size_t rbase = (size_t)blockIdx.x * NN;

    const float* xp0 = x + (rbase + w * 16 + lr) * CIN + lk * 8;
    bf16x8 wreg[4];                     // W chunk staging regs
    float4 xraw[2][2];                  // [ks][half] next-chunk X

    // ---- prologue: issue X chunk 0, stage W1 chunk 0 (swizzled) ----
    xraw[0][0] = *reinterpret_cast<const float4*>(xp0);
    xraw[0][1] = *reinterpret_cast<const float4*>(xp0 + 4);
    xraw[1][0] = *reinterpret_cast<const float4*>(xp0 + 32);
    xraw[1][1] = *reinterpret_cast<const float4*>(xp0 + 36);
    #pragma unroll
    for (int u = 0; u < 4; ++u) {
        int q = u * 256 + t, c = q >> 3, g = q & 7;
        wreg[u] = *reinterpret_cast<const bf16x8*>(W1h + (size_t)c * CIN + g * 8);
    }
    #pragma unroll
    for (int u = 0; u < 4; ++u) {
        int q = u * 256 + t, c = q >> 3, g = q & 7;
        *reinterpret_cast<bf16x8*>(&lds[c * 64 + ((g ^ (c & 7)) << 3)]) = wreg[u];
    }
    __syncthreads();

    f32x4 acc[8];
    #pragma unroll
    for (int ct = 0; ct < 8; ++ct)
        #pragma unroll
        for (int i = 0; i < 4; ++i) acc[ct][i] = 0.f;

    for (int kc = 0; kc < 8; ++kc) {
        const ushort_t* sWh = &lds[(kc & 1) * 8192];

        // convert previously-loaded X (latency covered) -> bf16 hi/lo
        bf16x8 xh[2], xl[2];
        #pragma unroll
        for (int ks = 0; ks < 2; ++ks) {
            const float xv[8] = {xraw[ks][0].x, xraw[ks][0].y, xraw[ks][0].z, xraw[ks][0].w,
                                 xraw[ks][1].x, xraw[ks][1].y, xraw[ks][1].z, xraw[ks][1].w};
            #pragma unroll
            for (int j = 0; j < 8; ++j) {
                ushort_t hh = f2bf(xv[j]);
                xh[ks][j] = (short)hh;
                xl[ks][j] = (short)f2bf(xv[j] - bf2f(hh));
            }
        }
        // issue next-chunk X + W loads (covered by this chunk's compute)
        if (kc < 7) {
            const float* xp = xp0 + (kc + 1) * 64;
            xraw[0][0] = *reinterpret_cast<const float4*>(xp);
            xraw[0][1] = *reinterpret_cast<const float4*>(xp + 4);
            xraw[1][0] = *reinterpret_cast<const float4*>(xp + 32);
            xraw[1][1] = *reinterpret_cast<const float4*>(xp + 36);
            #pragma unroll
            for (int u = 0; u < 4; ++u) {
                int q = u * 256 + t, c = q >> 3, g = q & 7;
                wreg[u] = *reinterpret_cast<const bf16x8*>(W1h + (size_t)c * CIN + (kc + 1) * 64 + g * 8);
            }
        }
        // compute chunk kc: 2-pass (xh*wh + xl*wh)
        #pragma unroll
        for (int ks = 0; ks < 2; ++ks) {
            const int swz = (((ks << 2) | lk) ^ lr7) << 3;
            #pragma unroll
            for (int ct = 0; ct < 8; ++ct) {
                const int c = ct * 16 + lr;
                bf16x8 wh = *reinterpret_cast<const bf16x8*>(&sWh[c * 64 + swz]);
                acc[ct] = __builtin_amdgcn_mfma_f32_16x16x32_bf16(xh[ks], wh, acc[ct], 0, 0, 0);
                acc[ct] = __builtin_amdgcn_mfma_f32_16x16x32_bf16(xl[ks], wh, acc[ct], 0, 0, 0);
            }
        }
        if (kc < 7) {
            const int nb = ((kc & 1) ^ 1) * 8192;
            #pragma unroll
            for (int u = 0; u < 4; ++u) {
                int q = u * 256 + t, c = q >> 3, g = q & 7;
                *reinterpret_cast<bf16x8*>(&lds[nb + c * 64 + ((g ^ (c & 7)) << 3)]) = wreg[u];
            }
        }
        __syncthreads();
    }

    // ================= tail (in-block, one batch) =================
    ushort_t* sYt = &lds[0];            // [c(128)][n(64)] swizzled
    ushort_t* sH1 = &lds[8192];         // [n(64)][c(128)] swizzled

    // ---- Y1 (registers) -> sYt, bf16 ----
    {
        const int n0 = w * 16 + lk * 4;
        const int gn = n0 >> 3, noff = n0 & 7;
        #pragma unroll
        for (int ct = 0; ct < 8; ++ct) {
            const int c = ct * 16 + lr;
            bf16x4 yv;
            #pragma unroll
            for (int r = 0; r < 4; ++r) yv[r] = (short)f2bf(acc[ct][r]);
            *reinterpret_cast<bf16x4*>(&sYt[c * 64 + ((gn ^ lr7) << 3) + noff]) = yv;
        }
    }
    __syncthreads();

    // ---- agg1: H1 = relu(A @ Y1 + b1) -> sH1 ----
    bf16x8 ahf[2], alf[2];              // [ks]
    #pragma unroll
    for (int ks = 0; ks < 2; ++ks) {
        const int nrow = w * 16 + lr;
        const int ko = ks * 32 + lk * 8;
        ahf[ks] = *reinterpret_cast<const bf16x8*>(Ah + nrow * NN + ko);
        alf[ks] = *reinterpret_cast<const bf16x8*>(Al + nrow * NN + ko);
    }
    {
        f32x4 hacc[8];
        #pragma unroll
        for (int ct = 0; ct < 8; ++ct)
            #pragma unroll
            for (int i = 0; i < 4; ++i) hacc[ct][i] = 0.f;
        #pragma unroll
        for (int ks = 0; ks < 2; ++ks) {
            const int swz = (((ks << 2) | lk) ^ lr7) << 3;
            #pragma unroll
            for (int ct = 0; ct < 8; ++ct) {
                const int c = ct * 16 + lr;
                bf16x8 y = *reinterpret_cast<const bf16x8*>(&sYt[c * 64 + swz]);
                hacc[ct] = __builtin_amdgcn_mfma_f32_16x16x32_bf16(ahf[ks], y, hacc[ct], 0, 0, 0);
                hacc[ct] = __builtin_amdgcn_mfma_f32_16x16x32_bf16(alf[ks], y, hacc[ct], 0, 0, 0);
            }
        }
        #pragma unroll
        for (int ct = 0; ct < 8; ++ct) {
            const int c = ct * 16 + lr;
            const int gc = c >> 3;
            const float bias = b1[c];
            #pragma unroll
            for (int r = 0; r < 4; ++r) {
                const int n = w * 16 + lk * 4 + r;
                float v = fmaxf(hacc[ct][r] + bias, 0.f);
                sH1[n * 128 + ((gc ^ (n & 7)) << 3) + (c & 7)] = f2bf(v);
            }
        }
    }
    __syncthreads();

    // ---- gemm2: Y2 = H1 @ W2h (1-pass); W2h staged in two 16KB k-halves
    //      into the dead sYt region ----
    f32x4 acc2[8];
    #pragma unroll
    for (int ct = 0; ct < 8; ++ct)
        #pragma unroll
        for (int i = 0; i < 4; ++i) acc2[ct][i] = 0.f;

    bf16x8 hf[4];                       // K=128 fragments of H1 (sH1 stable)
    {
        const int n = w * 16 + lr;
        #pragma unroll
        for (int ks = 0; ks < 4; ++ks) {
            const int gh = ((ks << 2) | lk) ^ (n & 7);
            hf[ks] = *reinterpret_cast<const bf16x8*>(&sH1[n * 128 + (gh << 3)]);
        }
    }
    #pragma unroll
    for (int kh = 0; kh < 2; ++kh) {
        // stage W2h k-half kh: [128c][64k] -> sYt region, swizzled
        #pragma unroll
        for (int u = 0; u < 4; ++u) {
            int idx = u * 256 + t;      // granule id 0..1023
            int c = idx >> 3, g = idx & 7;
            *reinterpret_cast<bf16x8*>(&lds[c * 64 + ((g ^ (c & 7)) << 3)]) =
                *reinterpret_cast<const bf16x8*>(W2h + (size_t)c * CH + kh * 64 + g * 8);
        }
        __syncthreads();
        #pragma unroll
        for (int ksl = 0; ksl < 2; ++ksl) {
            const int swz = (((ksl << 2) | lk) ^ lr7) << 3;
            #pragma unroll
            for (int ct = 0; ct < 8; ++ct) {
                const int c = ct * 16 + lr;
                bf16x8 w2 = *reinterpret_cast<const bf16x8*>(&lds[c * 64 + swz]);
                acc2[ct] = __builtin_amdgcn_mfma_f32_16x16x32_bf16(hf[kh * 2 + ksl], w2, acc2[ct], 0, 0, 0);
            }
        }
        __syncthreads();                // all reads done before next overwrite
    }

    // Y2 -> sYt
    {
        const int n0 = w * 16 + lk * 4;
        const int gn = n0 >> 3, noff = n0 & 7;
        #pragma unroll
        for (int ct = 0; ct < 8; ++ct) {
            const int c = ct * 16 + lr;
            bf16x4 yv;
            #pragma unroll
            for (int r = 0; r < 4; ++r) yv[r] = (short)f2bf(acc2[ct][r]);
            *reinterpret_cast<bf16x4*>(&sYt[c * 64 + ((gn ^ lr7) << 3) + noff]) = yv;
        }
    }
    __syncthreads();

    // ---- agg2 + bias + relu + FC ----
    float p0 = 0.f, p1 = 0.f;
    {
        f32x4 h2[8];
        #pragma unroll
        for (int ct = 0; ct < 8; ++ct)
            #pragma unroll
            for (int i = 0; i < 4; ++i) h2[ct][i] = 0.f;
        #pragma unroll
        for (int ks = 0; ks < 2; ++ks) {
            const int swz = (((ks << 2) | lk) ^ lr7) << 3;
            #pragma unroll
            for (int ct = 0; ct < 8; ++ct) {
                const int c = ct * 16 + lr;
                bf16x8 y = *reinterpret_cast<const bf16x8*>(&sYt[c * 64 + swz]);
                h2[ct] = __builtin_amdgcn_mfma_f32_16x16x32_bf16(ahf[ks], y, h2[ct], 0, 0, 0);
                h2[ct] = __builtin_amdgcn_mfma_f32_16x16x32_bf16(alf[ks], y, h2[ct], 0, 0, 0);
            }
        }
        #pragma unroll
        for (int ct = 0; ct < 8; ++ct) {
            const int c = ct * 16 + lr;
            const float bias = b2[c];
            #pragma unroll
            for (int r = 0; r < 4; ++r) {
                const int n = w * 16 + lk * 4 + r;
                float v = fmaxf(h2[ct][r] + bias, 0.f);
                const float2 fw = *reinterpret_cast<const float2*>(fcW + ((size_t)(n * CH + c)) * 2);
                p0 = fmaf(v, fw.x, p0);
                p1 = fmaf(v, fw.y, p1);
            }
        }
    }
    #pragma unroll
    for (int off = 32; off > 0; off >>= 1) {
        p0 += __shfl_down(p0, off);
        p1 += __shfl_down(p1, off);
    }
    if (l == 0) { sred[w * 2] = p0; sred[w * 2 + 1] = p1; }
    __syncthreads();
    if (t == 0) {
        const size_t b = blockIdx.x;
        out[b * 2 + 0] = sred[0] + sred[2] + sred[4] + sred[6] + fcb[0];
        out[b * 2 + 1] = sred[1] + sred[3] + sred[5] + sred[7] + fcb[1];
    }
}

// ---------------------------------------------------------------------------
extern "C" void kernel_launch(void* const* d_in, const int* in_sizes, int n_in,
                              void* d_out, int out_size, void* d_ws, size_t ws_size,
                              hipStream_t stream) {
    const float* x   = (const float*)d_in[0];
    const int*   ei  = (const int*)d_in[1];
    const float* W1  = (const float*)d_in[2];
    const float* b1  = (const float*)d_in[3];
    const float* W2  = (const float*)d_in[4];
    const float* b2  = (const float*)d_in[5];
    const float* fcW = (const float*)d_in[6];
    const float* fcb = (const float*)d_in[7];
    float* outp = (float*)d_out;

    // ws layout (bf16 elems): Ah,Al [64*64]; W1h [128*512]; W2h [128*128]
    ushort_t* Ah  = (ushort_t*)d_ws;
    ushort_t* Al  = Ah + NN * NN;
    ushort_t* W1h = Al + NN * NN;
    ushort_t* W2h = W1h + CIN * CH;    // total 180224 B

    const int E  = in_sizes[1] / 2;
    const int Bn = in_sizes[0] / (NN * CIN);

    prep_all<<<65, 256, 0, stream>>>(ei, E, W1, W2, Ah, Al, W1h, W2h);
    fused_all<<<Bn, 256, 0, stream>>>(x, W1h, Ah, Al, W2h,
                                      b1, b2, fcW, fcb, outp);
}

// Round 16
// 76.100 us; speedup vs baseline: 1.1034x; 1.0212x over previous
//
#include <hip/hip_runtime.h>
#include <cstddef>

// B=2048, N=64, C_IN=512, C_H=128, NUM_CLASSES=2, E=1024
#define NN   64
#define CIN  512
#define CH   128

typedef unsigned short ushort_t;
typedef __attribute__((ext_vector_type(8))) short bf16x8;
typedef __attribute__((ext_vector_type(4))) short bf16x4;
typedef __attribute__((ext_vector_type(4))) float f32x4;

__device__ __forceinline__ ushort_t f2bf(float f) {          // RN-even fp32->bf16
    union { float f; unsigned u; } v; v.f = f;
    unsigned r = v.u + 0x7fffu + ((v.u >> 16) & 1u);
    return (ushort_t)(r >> 16);
}
__device__ __forceinline__ float bf2f(ushort_t b) {
    union { unsigned u; float f; } v; v.u = ((unsigned)b) << 16;
    return v.f;
}

// ---------------------------------------------------------------------------
// Kernel 1: block 0 builds normalized adjacency A (hi/lo bf16); blocks 1..64
// transpose + bf16 W1 (hi only) and W2 (hi only).
// ---------------------------------------------------------------------------
__global__ __launch_bounds__(256) void prep_all(const int* __restrict__ ei, int E,
                                                const float* __restrict__ W1,
                                                const float* __restrict__ W2,
                                                ushort_t* __restrict__ Ah, ushort_t* __restrict__ Al,
                                                ushort_t* __restrict__ W1h,
                                                ushort_t* __restrict__ W2h) {
    const int t = threadIdx.x;
    if (blockIdx.x == 0) {
        __shared__ float sdeg[NN];
        __shared__ float snorm[NN];
        __shared__ float sA[NN * NN];
        if (t < NN) sdeg[t] = 0.f;
        for (int i = t; i < NN * NN; i += 256) sA[i] = 0.f;
        __syncthreads();
        for (int e = t; e < E; e += 256) atomicAdd(&sdeg[ei[E + e]], 1.0f);
        __syncthreads();
        if (t < NN) snorm[t] = rsqrtf(sdeg[t] + 1.0f);
        __syncthreads();
        for (int e = t; e < E; e += 256) {
            int s = ei[e], d = ei[E + e];
            atomicAdd(&sA[d * NN + s], snorm[s] * snorm[d]);
        }
        if (t < NN) atomicAdd(&sA[t * NN + t], snorm[t] * snorm[t]);
        __syncthreads();
        for (int i = t; i < NN * NN; i += 256) {
            float a = sA[i];
            ushort_t h = f2bf(a);
            Ah[i] = h;
            Al[i] = f2bf(a - bf2f(h));
        }
    } else {
        const int idx = (blockIdx.x - 1) * 256 + t;
        const int stride = 64 * 256;
        for (int i = idx; i < CIN * CH; i += stride) {
            int k = i / CH, c = i % CH;
            W1h[c * CIN + k] = f2bf(W1[i]);          // hi only
        }
        for (int i = idx; i < CH * CH; i += stride) {
            int k = i / CH, c = i % CH;
            W2h[c * CH + k] = f2bf(W2[i]);           // hi only
        }
    }
}

// ---------------------------------------------------------------------------
// Kernel 2: FULLY FUSED — R16 = R13 with X-HI ONLY gemm1 (1-pass).
// Diagnostic + optimization: halves gemm1 MFMA (32->16/chunk/wave), ~halves
// the fp32->bf16 conversion VALU, frees ~30 VGPR. A/B vs R13 isolates
// whether gemm1 chunk compute was on the critical path (if neutral ->
// delivery-bound -> roofline).
// Structure identical to R13: 256 thr = 4 waves; wave w owns rows
// [w*32,+32) (rf=2x16) x 128 cols (ct=8); block = 2 batches; W1 LDS dbuf
// (reg-staged, swizzled); 1-deep X register prefetch; tail = agg1 (A 2-pass)
// -> gemm2 (W2h from LDS, 1-pass) -> agg2 -> FC.
// LDS 64KB -> 2 blocks/CU. 16B-granule XOR swizzle: granule g of row r at
// slot g^(r&7) (both-sides, bijective).
// ---------------------------------------------------------------------------
__global__ __launch_bounds__(256, 2) void fused_all(
    const float* __restrict__ x,
    const ushort_t* __restrict__ W1h,
    const ushort_t* __restrict__ Ah, const ushort_t* __restrict__ Al,
    const ushort_t* __restrict__ W2h,
    const float* __restrict__ b1, const float* __restrict__ b2,
    const float* __restrict__ fcW, const float* __restrict__ fcb,
    float* __restrict__ out)
{
    __shared__ ushort_t lds[32768];     // 65536 B
    __shared__ float sred[16];

    const int t   = threadIdx.x;
    const int l   = t & 63;
    const int w   = t >> 6;             // 0..3
    const int lr  = l & 15;
    const int lk  = l >> 4;
    const int lr7 = lr & 7;
    const size_t rbase = (size_t)blockIdx.x * 128;

    const float* xp0 = x + (rbase + w * 32 + lr) * CIN + lk * 8;
    bf16x8 wreg[4];                     // W1 chunk staging regs
    float4 xraw[2][2][2];               // [rf][ks][half] next-chunk X

    // ---- prologue: issue X chunk 0, stage W1 chunk 0 (swizzled) ----
    #pragma unroll
    for (int rf = 0; rf < 2; ++rf) {
        const float* xp = xp0 + rf * 16 * CIN;
        xraw[rf][0][0] = *reinterpret_cast<const float4*>(xp);
        xraw[rf][0][1] = *reinterpret_cast<const float4*>(xp + 4);
        xraw[rf][1][0] = *reinterpret_cast<const float4*>(xp + 32);
        xraw[rf][1][1] = *reinterpret_cast<const float4*>(xp + 36);
    }
    #pragma unroll
    for (int u = 0; u < 4; ++u) {
        int q = u * 256 + t, c = q >> 3, g = q & 7;
        wreg[u] = *reinterpret_cast<const bf16x8*>(W1h + (size_t)c * CIN + g * 8);
    }
    #pragma unroll
    for (int u = 0; u < 4; ++u) {
        int q = u * 256 + t, c = q >> 3, g = q & 7;
        *reinterpret_cast<bf16x8*>(&lds[c * 64 + ((g ^ (c & 7)) << 3)]) = wreg[u];
    }
    __syncthreads();

    f32x4 acc[2][8];
    #pragma unroll
    for (int rf = 0; rf < 2; ++rf)
        #pragma unroll
        for (int ct = 0; ct < 8; ++ct)
            #pragma unroll
            for (int i = 0; i < 4; ++i) acc[rf][ct][i] = 0.f;

    for (int kc = 0; kc < 8; ++kc) {
        const ushort_t* sWh = &lds[(kc & 1) * 8192];

        // convert previously-loaded X (latency covered) -> bf16 hi ONLY
        bf16x8 xh[2][2];
        #pragma unroll
        for (int rf = 0; rf < 2; ++rf)
            #pragma unroll
            for (int ks = 0; ks < 2; ++ks) {
                const float xv[8] = {xraw[rf][ks][0].x, xraw[rf][ks][0].y,
                                     xraw[rf][ks][0].z, xraw[rf][ks][0].w,
                                     xraw[rf][ks][1].x, xraw[rf][ks][1].y,
                                     xraw[rf][ks][1].z, xraw[rf][ks][1].w};
                #pragma unroll
                for (int j = 0; j < 8; ++j)
                    xh[rf][ks][j] = (short)f2bf(xv[j]);
            }
        // issue next-chunk X + W1 loads (covered by this chunk's compute)
        if (kc < 7) {
            #pragma unroll
            for (int rf = 0; rf < 2; ++rf) {
                const float* xp = xp0 + rf * 16 * CIN + (kc + 1) * 64;
                xraw[rf][0][0] = *reinterpret_cast<const float4*>(xp);
                xraw[rf][0][1] = *reinterpret_cast<const float4*>(xp + 4);
                xraw[rf][1][0] = *reinterpret_cast<const float4*>(xp + 32);
                xraw[rf][1][1] = *reinterpret_cast<const float4*>(xp + 36);
            }
            #pragma unroll
            for (int u = 0; u < 4; ++u) {
                int q = u * 256 + t, c = q >> 3, g = q & 7;
                wreg[u] = *reinterpret_cast<const bf16x8*>(W1h + (size_t)c * CIN + (kc + 1) * 64 + g * 8);
            }
        }
        // compute chunk kc: 1-pass (xh*wh)
        #pragma unroll
        for (int ks = 0; ks < 2; ++ks) {
            const int swz = (((ks << 2) | lk) ^ lr7) << 3;
            #pragma unroll
            for (int ct = 0; ct < 8; ++ct) {
                const int c = ct * 16 + lr;
                bf16x8 wh = *reinterpret_cast<const bf16x8*>(&sWh[c * 64 + swz]);
                #pragma unroll
                for (int rf = 0; rf < 2; ++rf)
                    acc[rf][ct] = __builtin_amdgcn_mfma_f32_16x16x32_bf16(xh[rf][ks], wh, acc[rf][ct], 0, 0, 0);
            }
        }
        if (kc < 7) {
            const int nb = ((kc & 1) ^ 1) * 8192;
            #pragma unroll
            for (int u = 0; u < 4; ++u) {
                int q = u * 256 + t, c = q >> 3, g = q & 7;
                *reinterpret_cast<bf16x8*>(&lds[nb + c * 64 + ((g ^ (c & 7)) << 3)]) = wreg[u];
            }
        }
        __syncthreads();
    }

    // ================= tail (in-block) =================
    // sYt: batch qb at lds[qb*8192], tile [c(128)][n(64)] swizzled.
    // sH1: batch qb at lds[16384 + qb*8192], tile [n(64)][c(128)] swizzled.

    // ---- Y1 (registers) -> sYt, bf16 ----
    #pragma unroll
    for (int rf = 0; rf < 2; ++rf) {
        const int grow = w * 32 + rf * 16 + lk * 4;
        const int qb   = grow >> 6;
        const int n0   = grow & 63;
        const int gn   = n0 >> 3, noff = n0 & 7;
        #pragma unroll
        for (int ct = 0; ct < 8; ++ct) {
            const int c = ct * 16 + lr;
            bf16x4 yv;
            #pragma unroll
            for (int r = 0; r < 4; ++r) yv[r] = (short)f2bf(acc[rf][ct][r]);
            *reinterpret_cast<bf16x4*>(&lds[qb * 8192 + c * 64 + ((gn ^ lr7) << 3) + noff]) = yv;
        }
    }
    __syncthreads();

    const int q = w >> 1;               // batch within block
    const int h = w & 1;                // 32-row half
    ushort_t* sYtq = &lds[q * 8192];
    ushort_t* sH1q = &lds[16384 + q * 8192];

    // ---- agg1: H1 = relu(A @ Y1 + b1) -> sH1 ----
    bf16x8 ahf[2][2], alf[2][2];        // [rf][ks]
    #pragma unroll
    for (int rf = 0; rf < 2; ++rf)
        #pragma unroll
        for (int ks = 0; ks < 2; ++ks) {
            const int nrow = h * 32 + rf * 16 + lr;
            const int ko = ks * 32 + lk * 8;
            ahf[rf][ks] = *reinterpret_cast<const bf16x8*>(Ah + nrow * NN + ko);
            alf[rf][ks] = *reinterpret_cast<const bf16x8*>(Al + nrow * NN + ko);
        }
    {
        f32x4 hacc[2][8];
        #pragma unroll
        for (int rf = 0; rf < 2; ++rf)
            #pragma unroll
            for (int ct = 0; ct < 8; ++ct)
                #pragma unroll
                for (int i = 0; i < 4; ++i) hacc[rf][ct][i] = 0.f;
        #pragma unroll
        for (int ks = 0; ks < 2; ++ks) {
            const int swz = (((ks << 2) | lk) ^ lr7) << 3;
            #pragma unroll
            for (int ct = 0; ct < 8; ++ct) {
                const int c = ct * 16 + lr;
                bf16x8 y = *reinterpret_cast<const bf16x8*>(&sYtq[c * 64 + swz]);
                #pragma unroll
                for (int rf = 0; rf < 2; ++rf) {
                    hacc[rf][ct] = __builtin_amdgcn_mfma_f32_16x16x32_bf16(ahf[rf][ks], y, hacc[rf][ct], 0, 0, 0);
                    hacc[rf][ct] = __builtin_amdgcn_mfma_f32_16x16x32_bf16(alf[rf][ks], y, hacc[rf][ct], 0, 0, 0);
                }
            }
        }
        #pragma unroll
        for (int rf = 0; rf < 2; ++rf)
            #pragma unroll
            for (int ct = 0; ct < 8; ++ct) {
                const int c = ct * 16 + lr;
                const int gc = c >> 3;
                const float bias = b1[c];
                #pragma unroll
                for (int r = 0; r < 4; ++r) {
                    const int n = h * 32 + rf * 16 + lk * 4 + r;
                    float v = fmaxf(hacc[rf][ct][r] + bias, 0.f);
                    sH1q[n * 128 + ((gc ^ (n & 7)) << 3) + (c & 7)] = f2bf(v);
                }
            }
    }
    __syncthreads();

    // ---- stage W2h into LDS (sYt region; Y1 dead, Y2 not yet written) ----
    #pragma unroll
    for (int u = 0; u < 8; ++u) {
        int idx = u * 256 + t;          // granule id 0..2047
        int c = idx >> 4, g = idx & 15;
        *reinterpret_cast<bf16x8*>(&lds[c * 128 + ((g ^ (c & 7)) << 3)]) =
            *reinterpret_cast<const bf16x8*>(W2h + (size_t)c * CH + g * 8);
    }
    __syncthreads();

    // ---- gemm2: Y2 = H1 @ W2h (1-pass), W2 from LDS ----
    f32x4 acc2[2][8];
    #pragma unroll
    for (int rf = 0; rf < 2; ++rf)
        #pragma unroll
        for (int ct = 0; ct < 8; ++ct)
            #pragma unroll
            for (int i = 0; i < 4; ++i) acc2[rf][ct][i] = 0.f;
    {
        bf16x8 hf[2][4];                // [rf][ks], K=128
        #pragma unroll
        for (int rf = 0; rf < 2; ++rf) {
            const int n = h * 32 + rf * 16 + lr;
            #pragma unroll
            for (int ks = 0; ks < 4; ++ks) {
                const int gh = ((ks << 2) | lk) ^ (n & 7);
                hf[rf][ks] = *reinterpret_cast<const bf16x8*>(&sH1q[n * 128 + (gh << 3)]);
            }
        }
        #pragma unroll
        for (int ct = 0; ct < 8; ++ct) {
            const int c = ct * 16 + lr;
            #pragma unroll
            for (int ks = 0; ks < 4; ++ks) {
                const int gw = ((ks << 2) | lk) ^ (c & 7);
                bf16x8 w2 = *reinterpret_cast<const bf16x8*>(&lds[c * 128 + (gw << 3)]);
                #pragma unroll
                for (int rf = 0; rf < 2; ++rf)
                    acc2[rf][ct] = __builtin_amdgcn_mfma_f32_16x16x32_bf16(hf[rf][ks], w2, acc2[rf][ct], 0, 0, 0);
            }
        }
    }
    __syncthreads();                    // all W2h reads done before Y2 overwrite

    // Y2 -> sYt
    #pragma unroll
    for (int rf = 0; rf < 2; ++rf) {
        const int n0 = h * 32 + rf * 16 + lk * 4;
        const int gn = n0 >> 3, noff = n0 & 7;
        #pragma unroll
        for (int ct = 0; ct < 8; ++ct) {
            const int c = ct * 16 + lr;
            bf16x4 yv;
            #pragma unroll
            for (int r = 0; r < 4; ++r) yv[r] = (short)f2bf(acc2[rf][ct][r]);
            *reinterpret_cast<bf16x4*>(&sYtq[c * 64 + ((gn ^ lr7) << 3) + noff]) = yv;
        }
    }
    __syncthreads();

    // ---- agg2 + bias + relu + FC ----
    float p0 = 0.f, p1 = 0.f;
    {
        f32x4 h2[2][8];
        #pragma unroll
        for (int rf = 0; rf < 2; ++rf)
            #pragma unroll
            for (int ct = 0; ct < 8; ++ct)
                #pragma unroll
                for (int i = 0; i < 4; ++i) h2[rf][ct][i] = 0.f;
        #pragma unroll
        for (int ks = 0; ks < 2; ++ks) {
            const int swz = (((ks << 2) | lk) ^ lr7) << 3;
            #pragma unroll
            for (int ct = 0; ct < 8; ++ct) {
                const int c = ct * 16 + lr;
                bf16x8 y = *reinterpret_cast<const bf16x8*>(&sYtq[c * 64 + swz]);
                #pragma unroll
                for (int rf = 0; rf < 2; ++rf) {
                    h2[rf][ct] = __builtin_amdgcn_mfma_f32_16x16x32_bf16(ahf[rf][ks], y, h2[rf][ct], 0, 0, 0);
                    h2[rf][ct] = __builtin_amdgcn_mfma_f32_16x16x32_bf16(alf[rf][ks], y, h2[rf][ct], 0, 0, 0);
                }
            }
        }
        #pragma unroll
        for (int rf = 0; rf < 2; ++rf)
            #pragma unroll
            for (int ct = 0; ct < 8; ++ct) {
                const int c = ct * 16 + lr;
                const float bias = b2[c];
                #pragma unroll
                for (int r = 0; r < 4; ++r) {
                    const int n = h * 32 + rf * 16 + lk * 4 + r;
                    float v = fmaxf(h2[rf][ct][r] + bias, 0.f);
                    const float2 fw = *reinterpret_cast<const float2*>(fcW + ((size_t)(n * CH + c)) * 2);
                    p0 = fmaf(v, fw.x, p0);
                    p1 = fmaf(v, fw.y, p1);
                }
            }
    }
    #pragma unroll
    for (int off = 32; off > 0; off >>= 1) {
        p0 += __shfl_down(p0, off);
        p1 += __shfl_down(p1, off);
    }
    if (l == 0) { sred[w * 2] = p0; sred[w * 2 + 1] = p1; }
    __syncthreads();
    if (t == 0) {
        const size_t bA = (size_t)blockIdx.x * 2;
        out[bA * 2 + 0]       = sred[0] + sred[2] + fcb[0];
        out[bA * 2 + 1]       = sred[1] + sred[3] + fcb[1];
        out[(bA + 1) * 2 + 0] = sred[4] + sred[6] + fcb[0];
        out[(bA + 1) * 2 + 1] = sred[5] + sred[7] + fcb[1];
    }
}

// ---------------------------------------------------------------------------
extern "C" void kernel_launch(void* const* d_in, const int* in_sizes, int n_in,
                              void* d_out, int out_size, void* d_ws, size_t ws_size,
                              hipStream_t stream) {
    const float* x   = (const float*)d_in[0];
    const int*   ei  = (const int*)d_in[1];
    const float* W1  = (const float*)d_in[2];
    const float* b1  = (const float*)d_in[3];
    const float* W2  = (const float*)d_in[4];
    const float* b2  = (const float*)d_in[5];
    const float* fcW = (const float*)d_in[6];
    const float* fcb = (const float*)d_in[7];
    float* outp = (float*)d_out;

    // ws layout (bf16 elems): Ah,Al [64*64]; W1h [128*512]; W2h [128*128]
    ushort_t* Ah  = (ushort_t*)d_ws;
    ushort_t* Al  = Ah + NN * NN;
    ushort_t* W1h = Al + NN * NN;
    ushort_t* W2h = W1h + CIN * CH;    // total 180224 B

    const int E  = in_sizes[1] / 2;
    const int Bn = in_sizes[0] / (NN * CIN);

    prep_all<<<65, 256, 0, stream>>>(ei, E, W1, W2, Ah, Al, W1h, W2h);
    fused_all<<<Bn / 2, 256, 0, stream>>>(x, W1h, Ah, Al, W2h,
                                          b1, b2, fcW, fcb, outp);
}